// Round 1
// baseline (568.276 us; speedup 1.0000x reference)
//
#include <hip/hip_runtime.h>
#include <hip/hip_bf16.h>

#define DIM 384
#define HEADS 8
#define CP 48
#define NB 4
#define HIMG 128
#define WIMG 128
#define HW 16384

using bf16 = __hip_bfloat16;

typedef __attribute__((ext_vector_type(8))) short bf16x8;
typedef __attribute__((ext_vector_type(4))) float f32x4;

__device__ __forceinline__ float lo_bf(unsigned u){ union{unsigned i; float f;} c; c.i = u<<16; return c.f; }
__device__ __forceinline__ float hi_bf(unsigned u){ union{unsigned i; float f;} c; c.i = u & 0xffff0000u; return c.f; }
__device__ __forceinline__ bf16 f2bf(float v){ return __float2bfloat16(v); }
__device__ __forceinline__ unsigned short bfbits(float v){ union{ bf16 h; unsigned short u; } c; c.h = f2bf(v); return c.u; }
__device__ __forceinline__ float s2f(short s){ union{unsigned u; float f;} c; c.u = ((unsigned)(unsigned short)s) << 16; return c.f; }
__device__ __forceinline__ void cvt4(const short* p, float* o){
  uint2 u = *(const uint2*)p;
  o[0]=lo_bf(u.x); o[1]=hi_bf(u.x); o[2]=lo_bf(u.y); o[3]=hi_bf(u.y);
}

__device__ __forceinline__ float4 load4f(const float* p){ return *(const float4*)p; }
__device__ __forceinline__ float4 load4f(const bf16* p){
  uint2 u = *(const uint2*)p;
  float4 r; r.x = lo_bf(u.x); r.y = hi_bf(u.x); r.z = lo_bf(u.y); r.w = hi_bf(u.y); return r;
}

__device__ __forceinline__ void st(float* p, float v){ *p = v; }
__device__ __forceinline__ void st(bf16* p, float v){ *p = f2bf(v); }

#define GLD_LDS16(g, l) __builtin_amdgcn_global_load_lds( \
    (const __attribute__((address_space(1))) void*)(g), \
    (__attribute__((address_space(3))) void*)(l), 16, 0, 0)

// ---------------------------------------------------------------------------
// Weight fp32 -> bf16 (Wq 384x384, Wkv 768x384), one launch.
__global__ __launch_bounds__(256) void convert_w(
    const float* __restrict__ Wq, const float* __restrict__ Wkv,
    bf16* __restrict__ Wq_bf, bf16* __restrict__ Wkv_bf)
{
  int idx = (blockIdx.x*256 + threadIdx.x) * 2;
  const int NQ = DIM*DIM;           // 147456
  const int NKV = 2*DIM*DIM;        // 294912
  if (idx < NQ) {
    unsigned u = (unsigned)bfbits(Wq[idx]) | ((unsigned)bfbits(Wq[idx+1]) << 16);
    *(unsigned*)(Wq_bf + idx) = u;
  } else {
    int j = idx - NQ;
    if (j < NKV) {
      unsigned u = (unsigned)bfbits(Wkv[j]) | ((unsigned)bfbits(Wkv[j+1]) << 16);
      *(unsigned*)(Wkv_bf + j) = u;
    }
  }
}

// ---------------------------------------------------------------------------
// Transpose + cast: in [C][HW] (TIn) -> out [HW][C] (bf16). 64x64 tiles.
// For TIn=float: gridDim.z = 8 (z<4 -> tensor0, else tensor1).
template<typename TIn>
__global__ __launch_bounds__(256) void transpose_cast(
    const TIn* __restrict__ in0, const TIn* __restrict__ in1,
    bf16* __restrict__ out0, bf16* __restrict__ out1,
    long inBatchStride, long outBatchStride)
{
  const int zb = blockIdx.z;
  const TIn* in = (zb < NB) ? in0 : in1;
  bf16* outp = (zb < NB) ? out0 : out1;
  const int b = zb & 3;
  const int n0 = blockIdx.x * 64;
  const int c0 = blockIdx.y * 64;
  const TIn* inb = in + (long)b * inBatchStride;
  bf16* outb = outp + (long)b * outBatchStride;

  __shared__ float tile[64][66];
  const int t = threadIdx.x;
#pragma unroll
  for (int i = 0; i < 4; ++i) {
    int g = i*256 + t;
    int r = g >> 4, c4 = g & 15;
    float4 v = load4f(inb + (long)(c0 + r)*HW + n0 + c4*4);
    tile[r][c4*4+0] = v.x; tile[r][c4*4+1] = v.y;
    tile[r][c4*4+2] = v.z; tile[r][c4*4+3] = v.w;
  }
  __syncthreads();
#pragma unroll
  for (int i = 0; i < 8; ++i) {
    int g = i*256 + t;
    int n = g >> 5, cu = g & 31;
    unsigned u = (unsigned)bfbits(tile[cu*2][n]) | ((unsigned)bfbits(tile[cu*2+1][n]) << 16);
    *(unsigned*)(outb + (long)(n0 + n)*DIM + c0 + cu*2) = u;
  }
}

// ---------------------------------------------------------------------------
// MFMA GEMM: C[b][m][n] = sum_k A[m][k] * Bt[b][n][k],  n in [0,HW)
// A bf16 row-major (aStride==0 -> shared across b), Bt bf16 [HW][K] per batch.
// Tile 128x128, BK=64, 4 waves (each 64x64), global_load_lds + XOR swizzle.
template<typename TOut>
__global__ __launch_bounds__(256) void gemm_mfma(
    const bf16* __restrict__ A, long aStride,
    const bf16* __restrict__ Bt, TOut* __restrict__ C, int M, int K)
{
  const int b  = blockIdx.z;
  const int m0 = blockIdx.y * 128;
  const int n0 = blockIdx.x * 128;
  const bf16* Ab  = A  + (long)b * aStride;
  const bf16* Btb = Bt + (long)b * (long)HW * K;
  TOut* Cb = C + (long)b * (long)M * HW;

  __shared__ short As[128*64];
  __shared__ short Bs[128*64];

  const int t = threadIdx.x;
  const int w = t >> 6, lane = t & 63;
  const int quad = lane >> 4, l16 = lane & 15;
  const int wm = (w >> 1) * 64, wn = (w & 1) * 64;

  // staging pointers: chunk f = w*256 + i*64 + lane; r=f>>3, p=f&7, c=p^(r&7)
  const bf16* gA[4]; const bf16* gB[4];
#pragma unroll
  for (int i = 0; i < 4; ++i) {
    int f = w*256 + i*64 + lane;
    int r = f >> 3, p = f & 7;
    int c = p ^ (r & 7);
    gA[i] = Ab  + (long)(m0 + r)*K + c*8;
    gB[i] = Btb + (long)(n0 + r)*K + c*8;
  }

  f32x4 acc[4][4] = {};

  for (int k0 = 0; k0 < K; k0 += 64) {
#pragma unroll
    for (int i = 0; i < 4; ++i) {
      GLD_LDS16(gA[i], As + (w*256 + i*64)*8);
      GLD_LDS16(gB[i], Bs + (w*256 + i*64)*8);
      gA[i] += 64; gB[i] += 64;
    }
    __syncthreads();
#pragma unroll
    for (int kk = 0; kk < 2; ++kk) {
      bf16x8 af[4], bfr[4];
      const int sw = (kk*4 + quad) ^ (l16 & 7);
#pragma unroll
      for (int mt = 0; mt < 4; ++mt) {
        af[mt]  = *(const bf16x8*)(As + (wm + mt*16 + l16)*64 + sw*8);
        bfr[mt] = *(const bf16x8*)(Bs + (wn + mt*16 + l16)*64 + sw*8);
      }
#pragma unroll
      for (int mt = 0; mt < 4; ++mt)
#pragma unroll
        for (int nt = 0; nt < 4; ++nt)
          acc[mt][nt] = __builtin_amdgcn_mfma_f32_16x16x32_bf16(af[mt], bfr[nt], acc[mt][nt], 0, 0, 0);
    }
    __syncthreads();
  }

#pragma unroll
  for (int mt = 0; mt < 4; ++mt)
#pragma unroll
    for (int nt = 0; nt < 4; ++nt)
#pragma unroll
      for (int j = 0; j < 4; ++j) {
        int row = m0 + wm + mt*16 + quad*4 + j;
        int col = n0 + wn + nt*16 + l16;
        st(Cb + (long)row*HW + col, acc[mt][nt][j]);
      }
}

// ---------------------------------------------------------------------------
// Depthwise 3x3 SAME, IN-PLACE, one block per (channel, batch).
// Two-phase: stage 66 rows (zero halo) in LDS -> 18.5 KB -> 8 blocks/CU.
// Phase A computes rows 0..63, phase B rows 64..127; the phase-B top halo
// (input rows 63,64) is carried in registers across the phase-A writeback.
// Vectorized uint2 LDS reads, no edge masks/branches, lane-contiguous
// full-line global writeback via LDS. Also per-(b,ch) sum-of-squares (q/k).
__global__ __launch_bounds__(256, 6) void dwconv_inplace(
    bf16* __restrict__ qb, bf16* __restrict__ kvb,
    const float* __restrict__ Wdw, float* __restrict__ ssq)
{
  const int ch = blockIdx.x;   // 0..1151 (q:0..383, k:384..767, v:768..1151)
  const int b  = blockIdx.y;
  bf16* plane = (ch < DIM) ? qb + ((long)b*DIM + ch)*HW
                           : kvb + ((long)b*2*DIM + (ch - DIM))*HW;
  float w9[9];
#pragma unroll
  for (int i = 0; i < 9; ++i) w9[i] = Wdw[ch*9 + i];

  __shared__ short t_[66*140];   // 66 rows x 140 shorts (cols 128..131 zero pad)
  __shared__ float wsum[4];
  const int t = threadIdx.x;

  // zero right-pad columns 128..131 for all rows (persists through phases)
  if (t < 66) *(uint2*)&t_[t*140 + 128] = make_uint2(0u, 0u);

  // ---- phase A staging: input rows -1..64 -> lds rows 0..65 (row -1 = zeros)
#pragma unroll
  for (int i = 0; i < 9; ++i) {
    int chunk = i*256 + t;
    if (chunk < 66*32) {
      int r = chunk >> 5, c8 = chunk & 31;
      int gh = r - 1;
      uint2 v = make_uint2(0u, 0u);
      if (gh >= 0) v = *(const uint2*)(plane + gh*128 + c8*4);
      *(uint2*)&t_[r*140 + c8*4] = v;
    }
  }
  __syncthreads();                                   // s1

  const int r  = t >> 2;        // output row within phase: 0..63
  const int q  = t & 3;
  const int c0 = q * 32;
  float ss = 0.f;
  unsigned outu[16];

  auto compute = [&]() {
    const short* rT = t_ + (r    )*140 + c0;
    const short* rM = t_ + (r + 1)*140 + c0;
    const short* rB = t_ + (r + 2)*140 + c0;
    float at[4], am[4], ab[4];
    cvt4(rT, at); cvt4(rM, am); cvt4(rB, ab);
    float lt, lm, lb;
    if (q == 0) { lt = lm = lb = 0.f; }
    else { lt = s2f(rT[-1]); lm = s2f(rM[-1]); lb = s2f(rB[-1]); }
#pragma unroll
    for (int jb = 0; jb < 32; jb += 4) {
      float bt[4], bm[4], bb[4];
      cvt4(rT + jb + 4, bt);
      cvt4(rM + jb + 4, bm);
      cvt4(rB + jb + 4, bb);
      float o0 = w9[0]*lt    + w9[1]*at[0] + w9[2]*at[1]
               + w9[3]*lm    + w9[4]*am[0] + w9[5]*am[1]
               + w9[6]*lb    + w9[7]*ab[0] + w9[8]*ab[1];
      float o1 = w9[0]*at[0] + w9[1]*at[1] + w9[2]*at[2]
               + w9[3]*am[0] + w9[4]*am[1] + w9[5]*am[2]
               + w9[6]*ab[0] + w9[7]*ab[1] + w9[8]*ab[2];
      float o2 = w9[0]*at[1] + w9[1]*at[2] + w9[2]*at[3]
               + w9[3]*am[1] + w9[4]*am[2] + w9[5]*am[3]
               + w9[6]*ab[1] + w9[7]*ab[2] + w9[8]*ab[3];
      float o3 = w9[0]*at[2] + w9[1]*at[3] + w9[2]*bt[0]
               + w9[3]*am[2] + w9[4]*am[3] + w9[5]*bm[0]
               + w9[6]*ab[2] + w9[7]*ab[3] + w9[8]*bb[0];
      ss += o0*o0 + o1*o1 + o2*o2 + o3*o3;
      outu[(jb>>1)  ] = (unsigned)bfbits(o0) | ((unsigned)bfbits(o1) << 16);
      outu[(jb>>1)+1] = (unsigned)bfbits(o2) | ((unsigned)bfbits(o3) << 16);
      lt = at[3]; lm = am[3]; lb = ab[3];
#pragma unroll
      for (int u2 = 0; u2 < 4; ++u2) { at[u2]=bt[u2]; am[u2]=bm[u2]; ab[u2]=bb[u2]; }
    }
  };

  // ---- phase A compute (reads lds rows 0..65)
  compute();
  // capture phase-B top halo (input rows 63,64 = lds rows 64,65) into regs
  uint2 halo = make_uint2(0u, 0u);
  if (t < 64) halo = *(const uint2*)&t_[(64 + (t >> 5))*140 + (t & 31)*4];
  __syncthreads();                                   // s2: all lds reads done

  // stage outputs into lds rows 0..63, then lane-contiguous global writeback
#pragma unroll
  for (int i2 = 0; i2 < 8; ++i2)
    *(uint2*)&t_[r*140 + c0 + i2*4] = *(uint2*)&outu[i2*2];
  __syncthreads();                                   // s3
#pragma unroll
  for (int i2 = 0; i2 < 4; ++i2) {
    int chunk = i2*256 + t;
    int orow = chunk >> 4, ocol = (chunk & 15)*8;
    uint2 lo = *(const uint2*)&t_[orow*140 + ocol];
    uint2 hi = *(const uint2*)&t_[orow*140 + ocol + 4];
    *(uint4*)(plane + (long)orow*128 + ocol) = make_uint4(lo.x, lo.y, hi.x, hi.y);
  }
  __syncthreads();                                   // s4: writeback reads done

  // ---- phase B staging: halo regs -> rows 0,1 ; global rows 65..128 -> rows 2..65
  if (t < 64) *(uint2*)&t_[(t >> 5)*140 + (t & 31)*4] = halo;
#pragma unroll
  for (int i2 = 0; i2 < 8; ++i2) {
    int chunk = i2*256 + t;          // 0..2047
    int rr = chunk >> 5, c8 = chunk & 31;
    int gh = 65 + rr;                // 65..128 (row 128 = zeros)
    uint2 v = make_uint2(0u, 0u);
    if (gh < 128) v = *(const uint2*)(plane + gh*128 + c8*4);
    *(uint2*)&t_[(rr + 2)*140 + c8*4] = v;
  }
  __syncthreads();                                   // s5

  // ---- phase B compute (output rows 64..127)
  compute();
  __syncthreads();                                   // s6
#pragma unroll
  for (int i2 = 0; i2 < 8; ++i2)
    *(uint2*)&t_[r*140 + c0 + i2*4] = *(uint2*)&outu[i2*2];
  __syncthreads();                                   // s7
#pragma unroll
  for (int i2 = 0; i2 < 4; ++i2) {
    int chunk = i2*256 + t;
    int orow = chunk >> 4, ocol = (chunk & 15)*8;
    uint2 lo = *(const uint2*)&t_[orow*140 + ocol];
    uint2 hi = *(const uint2*)&t_[orow*140 + ocol + 4];
    *(uint4*)(plane + (long)(64 + orow)*128 + ocol) = make_uint4(lo.x, lo.y, hi.x, hi.y);
  }

  // ---- ssq reduction over both phases (q/k channels only)
  if (ch < 2*DIM) {
#pragma unroll
    for (int off = 32; off; off >>= 1) ss += __shfl_down(ss, off);
    if ((t & 63) == 0) wsum[t >> 6] = ss;
    __syncthreads();
    if (t == 0) ssq[b*2*DIM + ch] = wsum[0]+wsum[1]+wsum[2]+wsum[3];
  }
}

// ---------------------------------------------------------------------------
// S slabs: Sp[split][b][h][48][48] = sum over this split's n-range of q.k^T
// 512 threads = 8 waves; slice = split*8 + wave; 256 n per slice (8 ksteps).
__global__ __launch_bounds__(512) void s_mfma(
    const bf16* __restrict__ qd, const bf16* __restrict__ kd,
    float* __restrict__ Sp)
{
  const int split = blockIdx.x;  // 0..7
  const int h = blockIdx.y, b = blockIdx.z;
  const int t = threadIdx.x, w = t >> 6, lane = t & 63;
  const int quad = lane >> 4, l16 = lane & 15;
  const bf16* qp = qd + ((long)b*DIM + h*CP)*HW;
  const bf16* kp = kd + ((long)b*DIM + h*CP)*HW;
  const int nbase = (split*8 + w) * 256;

  f32x4 acc[3][3] = {};
  for (int ks = 0; ks < 8; ++ks) {
    const int n = nbase + ks*32 + quad*8;
    bf16x8 aq[3], bk[3];
#pragma unroll
    for (int i = 0; i < 3; ++i) {
      aq[i] = *(const bf16x8*)(qp + (long)(i*16 + l16)*HW + n);
      bk[i] = *(const bf16x8*)(kp + (long)(i*16 + l16)*HW + n);
    }
#pragma unroll
    for (int i = 0; i < 3; ++i)
#pragma unroll
      for (int j = 0; j < 3; ++j)
        acc[i][j] = __builtin_amdgcn_mfma_f32_16x16x32_bf16(aq[i], bk[j], acc[i][j], 0, 0, 0);
  }

  __shared__ float Sred[8][CP*CP];
#pragma unroll
  for (int i = 0; i < 3; ++i)
#pragma unroll
    for (int j = 0; j < 3; ++j)
#pragma unroll
      for (int rr = 0; rr < 4; ++rr)
        Sred[w][(i*16 + quad*4 + rr)*CP + j*16 + l16] = acc[i][j][rr];
  __syncthreads();

  float* out = Sp + (long)split*(NB*HEADS*CP*CP) + ((long)(b*HEADS + h))*CP*CP;
  for (int g = t; g < CP*CP; g += 512) {
    float s = 0.f;
#pragma unroll
    for (int ww = 0; ww < 8; ++ww) s += Sred[ww][g];
    out[g] = s;
  }
}

// ---------------------------------------------------------------------------
// logit = (sum slabs) * rsqrt(ssq_q[c]) * rsqrt(ssq_k[d]) * temp[h]; softmax
// over d; writes into slab 0 (attn).
__global__ __launch_bounds__(64) void softmax_attn(
    float* __restrict__ Sp, const float* __restrict__ ssq,
    const float* __restrict__ temp)
{
  const int bhc = blockIdx.x;
  const int c = bhc % CP;
  const int h = (bhc / CP) % HEADS;
  const int b = bhc / (CP * HEADS);
  const int lane = threadIdx.x;
  const long rowoff = ((long)(b*HEADS + h))*CP*CP + c*CP;
  const float rq = rsqrtf(ssq[b*2*DIM + h*CP + c]);
  const float tmp = temp[h];
  float logit = -1e30f;
  if (lane < CP) {
    float s = 0.f;
#pragma unroll
    for (int sl = 0; sl < 8; ++sl) s += Sp[(long)sl*(NB*HEADS*CP*CP) + rowoff + lane];
    float rk = rsqrtf(ssq[b*2*DIM + DIM + h*CP + lane]);
    logit = s * rq * rk * tmp;
  }
  float m = logit;
#pragma unroll
  for (int off = 32; off; off >>= 1) m = fmaxf(m, __shfl_down(m, off));
  m = __shfl(m, 0);
  float e = (lane < CP) ? __expf(logit - m) : 0.f;
  float s = e;
#pragma unroll
  for (int off = 32; off; off >>= 1) s += __shfl_down(s, off);
  s = __shfl(s, 0);
  if (lane < CP) Sp[rowoff + lane] = e / s;
}

// ---------------------------------------------------------------------------
// W2[b, o, h*48+d] = sum_c Wproj[o, h*48+c] * attn[b,h,c,d]   (bf16 out)
__global__ __launch_bounds__(256) void w2fold(
    const float* __restrict__ attn, const float* __restrict__ Wproj,
    bf16* __restrict__ W2)
{
  const int ot = blockIdx.x;  // o-tile of 128 (3 tiles)
  const int h  = blockIdx.y;
  const int b  = blockIdx.z;
  __shared__ float at[CP][CP];
  __shared__ float wp[128][CP];
  const int t = threadIdx.x;
  const float* Ap = attn + ((long)(b*HEADS + h))*CP*CP;
#pragma unroll
  for (int i = 0; i < 9; ++i) {
    int idx = t + 256*i;
    at[idx / CP][idx % CP] = Ap[idx];
  }
#pragma unroll
  for (int i = 0; i < 24; ++i) {
    int idx = t + 256*i;
    int o = idx / CP, c = idx % CP;
    wp[o][c] = Wproj[(long)(ot*128 + o)*DIM + h*CP + c];
  }
  __syncthreads();
#pragma unroll
  for (int i = 0; i < 24; ++i) {
    int idx = t + 256*i;
    int o = idx / CP, d = idx % CP;
    float a = 0.f;
#pragma unroll
    for (int c = 0; c < CP; ++c) a += wp[o][c] * at[c][d];
    W2[((long)b*DIM + ot*128 + o)*DIM + h*CP + d] = f2bf(a);
  }
}

// ---------------------------------------------------------------------------
extern "C" void kernel_launch(void* const* d_in, const int* in_sizes, int n_in,
                              void* d_out, int out_size, void* d_ws, size_t ws_size,
                              hipStream_t stream) {
  const float* x     = (const float*)d_in[0];
  const float* y     = (const float*)d_in[1];
  const float* Wq    = (const float*)d_in[2];
  const float* Wkv   = (const float*)d_in[3];
  const float* Wdw   = (const float*)d_in[4];
  const float* Wproj = (const float*)d_in[5];
  const float* temp  = (const float*)d_in[6];
  float* out = (float*)d_out;

  char* ws = (char*)d_ws;
  const long SZ_T  = 50331648L;                 // one [HW][384] bf16 tensor per 4 batches
  bf16* xT    = (bf16*)(ws + 0L);               // later: vdT
  bf16* yT    = (bf16*)(ws + SZ_T);
  bf16* q_bf  = (bf16*)(ws + 2*SZ_T);           // dwconv in-place -> qd
  bf16* kv_bf = (bf16*)(ws + 3*SZ_T);           // 100663296; in-place -> kd, vd
  char* tail  = ws + 5*SZ_T;                    // 251658240
  bf16* Wq_bf  = (bf16*)(tail);                 // 294912   (dead before Sp)
  bf16* Wkv_bf = (bf16*)(tail + 294912L);       // 589824   (dead before Sp)
  float* Sp    = (float*)(tail);                // 8 slabs x 294912 = 2359296; slab0 -> attn
  bf16* W2_bf  = (bf16*)(tail + 294912L);       // 1179648  (over dead slabs 1-4)
  float* ssq   = (float*)(tail + 2359296L);     // 12288
  bf16* vdT    = xT;
  bf16* vd     = kv_bf + (long)DIM*HW;          // v slice base (batch stride 2*DIM*HW)

  // 1. weights -> bf16
  convert_w<<<864, 256, 0, stream>>>(Wq, Wkv, Wq_bf, Wkv_bf);
  // 2. x,y -> [hw][c] bf16
  transpose_cast<float><<<dim3(HW/64, DIM/64, 8), 256, 0, stream>>>(
      x, y, xT, yT, (long)DIM*HW, (long)HW*DIM);
  // 3. q = Wq @ x
  gemm_mfma<bf16><<<dim3(HW/128, DIM/128, NB), 256, 0, stream>>>(
      Wq_bf, 0, xT, q_bf, DIM, DIM);
  // 4. kv = Wkv @ y
  gemm_mfma<bf16><<<dim3(HW/128, 2*DIM/128, NB), 256, 0, stream>>>(
      Wkv_bf, 0, yT, kv_bf, 2*DIM, DIM);
  // 5. depthwise 3x3 in-place + ssq (two-phase, 18.5 KB LDS, 8 blocks/CU)
  dwconv_inplace<<<dim3(3*DIM, NB), 256, 0, stream>>>(q_bf, kv_bf, Wdw, ssq);
  // 6. vd -> [hw][c]
  transpose_cast<bf16><<<dim3(HW/64, DIM/64, NB), 256, 0, stream>>>(
      vd, nullptr, vdT, nullptr, (long)2*DIM*HW, (long)HW*DIM);
  // 7. raw scores (8 slabs)
  s_mfma<<<dim3(8, HEADS, NB), 512, 0, stream>>>(q_bf, kv_bf, Sp);
  // 8. softmax with folded l2norm + temperature (into slab 0)
  softmax_attn<<<dim3(NB*HEADS*CP), 64, 0, stream>>>(Sp, ssq, temp);
  // 9. fold Wproj through attn -> bf16
  w2fold<<<dim3(3, HEADS, NB), 256, 0, stream>>>(Sp, Wproj, W2_bf);
  // 10. out = W2 @ vd
  gemm_mfma<float><<<dim3(HW/128, DIM/128, NB), 256, 0, stream>>>(
      W2_bf, (long)DIM*DIM, vdT, out, DIM, DIM);
}

// Round 2
// 495.715 us; speedup vs baseline: 1.1464x; 1.1464x over previous
//
#include <hip/hip_runtime.h>
#include <hip/hip_bf16.h>

#define DIM 384
#define HEADS 8
#define CP 48
#define NB 4
#define HIMG 128
#define WIMG 128
#define HW 16384

using bf16 = __hip_bfloat16;

typedef __attribute__((ext_vector_type(8))) short bf16x8;
typedef __attribute__((ext_vector_type(4))) float f32x4;

__device__ __forceinline__ float lo_bf(unsigned u){ union{unsigned i; float f;} c; c.i = u<<16; return c.f; }
__device__ __forceinline__ float hi_bf(unsigned u){ union{unsigned i; float f;} c; c.i = u & 0xffff0000u; return c.f; }
__device__ __forceinline__ bf16 f2bf(float v){ return __float2bfloat16(v); }
__device__ __forceinline__ unsigned short bfbits(float v){ union{ bf16 h; unsigned short u; } c; c.h = f2bf(v); return c.u; }
__device__ __forceinline__ float s2f(short s){ union{unsigned u; float f;} c; c.u = ((unsigned)(unsigned short)s) << 16; return c.f; }
__device__ __forceinline__ void cvt4(const short* p, float* o){
  uint2 u = *(const uint2*)p;
  o[0]=lo_bf(u.x); o[1]=hi_bf(u.x); o[2]=lo_bf(u.y); o[3]=hi_bf(u.y);
}

__device__ __forceinline__ float4 load4f(const float* p){ return *(const float4*)p; }
__device__ __forceinline__ float4 load4f(const bf16* p){
  uint2 u = *(const uint2*)p;
  float4 r; r.x = lo_bf(u.x); r.y = hi_bf(u.x); r.z = lo_bf(u.y); r.w = hi_bf(u.y); return r;
}

__device__ __forceinline__ void st(float* p, float v){ *p = v; }
__device__ __forceinline__ void st(bf16* p, float v){ *p = f2bf(v); }

#define GLD_LDS16(g, l) __builtin_amdgcn_global_load_lds( \
    (const __attribute__((address_space(1))) void*)(g), \
    (__attribute__((address_space(3))) void*)(l), 16, 0, 0)

// ---------------------------------------------------------------------------
// Weight fp32 -> bf16 (Wq 384x384, Wkv 768x384), one launch.
__global__ __launch_bounds__(256) void convert_w(
    const float* __restrict__ Wq, const float* __restrict__ Wkv,
    bf16* __restrict__ Wq_bf, bf16* __restrict__ Wkv_bf)
{
  int idx = (blockIdx.x*256 + threadIdx.x) * 2;
  const int NQ = DIM*DIM;           // 147456
  const int NKV = 2*DIM*DIM;        // 294912
  if (idx < NQ) {
    unsigned u = (unsigned)bfbits(Wq[idx]) | ((unsigned)bfbits(Wq[idx+1]) << 16);
    *(unsigned*)(Wq_bf + idx) = u;
  } else {
    int j = idx - NQ;
    if (j < NKV) {
      unsigned u = (unsigned)bfbits(Wkv[j]) | ((unsigned)bfbits(Wkv[j+1]) << 16);
      *(unsigned*)(Wkv_bf + j) = u;
    }
  }
}

// ---------------------------------------------------------------------------
// Transpose + cast: in [C][HW] (TIn) -> out [HW][C] (bf16). 64x64 tiles.
// For TIn=float: gridDim.z = 8 (z<4 -> tensor0, else tensor1).
template<typename TIn>
__global__ __launch_bounds__(256) void transpose_cast(
    const TIn* __restrict__ in0, const TIn* __restrict__ in1,
    bf16* __restrict__ out0, bf16* __restrict__ out1,
    long inBatchStride, long outBatchStride)
{
  const int zb = blockIdx.z;
  const TIn* in = (zb < NB) ? in0 : in1;
  bf16* outp = (zb < NB) ? out0 : out1;
  const int b = zb & 3;
  const int n0 = blockIdx.x * 64;
  const int c0 = blockIdx.y * 64;
  const TIn* inb = in + (long)b * inBatchStride;
  bf16* outb = outp + (long)b * outBatchStride;

  __shared__ float tile[64][66];
  const int t = threadIdx.x;
#pragma unroll
  for (int i = 0; i < 4; ++i) {
    int g = i*256 + t;
    int r = g >> 4, c4 = g & 15;
    float4 v = load4f(inb + (long)(c0 + r)*HW + n0 + c4*4);
    tile[r][c4*4+0] = v.x; tile[r][c4*4+1] = v.y;
    tile[r][c4*4+2] = v.z; tile[r][c4*4+3] = v.w;
  }
  __syncthreads();
#pragma unroll
  for (int i = 0; i < 8; ++i) {
    int g = i*256 + t;
    int n = g >> 5, cu = g & 31;
    unsigned u = (unsigned)bfbits(tile[cu*2][n]) | ((unsigned)bfbits(tile[cu*2+1][n]) << 16);
    *(unsigned*)(outb + (long)(n0 + n)*DIM + c0 + cu*2) = u;
  }
}

// ---------------------------------------------------------------------------
// MFMA GEMM: C[b][m][n] = sum_k A[m][k] * Bt[b][n][k],  n in [0,HW)
// A bf16 row-major (aStride==0 -> shared across b), Bt bf16 [HW][K] per batch.
// Tile 128x128, BK=64, 4 waves (each 64x64), global_load_lds + XOR swizzle.
template<typename TOut>
__global__ __launch_bounds__(256) void gemm_mfma(
    const bf16* __restrict__ A, long aStride,
    const bf16* __restrict__ Bt, TOut* __restrict__ C, int M, int K)
{
  const int b  = blockIdx.z;
  const int m0 = blockIdx.y * 128;
  const int n0 = blockIdx.x * 128;
  const bf16* Ab  = A  + (long)b * aStride;
  const bf16* Btb = Bt + (long)b * (long)HW * K;
  TOut* Cb = C + (long)b * (long)M * HW;

  __shared__ short As[128*64];
  __shared__ short Bs[128*64];

  const int t = threadIdx.x;
  const int w = t >> 6, lane = t & 63;
  const int quad = lane >> 4, l16 = lane & 15;
  const int wm = (w >> 1) * 64, wn = (w & 1) * 64;

  // staging pointers: chunk f = w*256 + i*64 + lane; r=f>>3, p=f&7, c=p^(r&7)
  const bf16* gA[4]; const bf16* gB[4];
#pragma unroll
  for (int i = 0; i < 4; ++i) {
    int f = w*256 + i*64 + lane;
    int r = f >> 3, p = f & 7;
    int c = p ^ (r & 7);
    gA[i] = Ab  + (long)(m0 + r)*K + c*8;
    gB[i] = Btb + (long)(n0 + r)*K + c*8;
  }

  f32x4 acc[4][4] = {};

  for (int k0 = 0; k0 < K; k0 += 64) {
#pragma unroll
    for (int i = 0; i < 4; ++i) {
      GLD_LDS16(gA[i], As + (w*256 + i*64)*8);
      GLD_LDS16(gB[i], Bs + (w*256 + i*64)*8);
      gA[i] += 64; gB[i] += 64;
    }
    __syncthreads();
#pragma unroll
    for (int kk = 0; kk < 2; ++kk) {
      bf16x8 af[4], bfr[4];
      const int sw = (kk*4 + quad) ^ (l16 & 7);
#pragma unroll
      for (int mt = 0; mt < 4; ++mt) {
        af[mt]  = *(const bf16x8*)(As + (wm + mt*16 + l16)*64 + sw*8);
        bfr[mt] = *(const bf16x8*)(Bs + (wn + mt*16 + l16)*64 + sw*8);
      }
#pragma unroll
      for (int mt = 0; mt < 4; ++mt)
#pragma unroll
        for (int nt = 0; nt < 4; ++nt)
          acc[mt][nt] = __builtin_amdgcn_mfma_f32_16x16x32_bf16(af[mt], bfr[nt], acc[mt][nt], 0, 0, 0);
    }
    __syncthreads();
  }

#pragma unroll
  for (int mt = 0; mt < 4; ++mt)
#pragma unroll
    for (int nt = 0; nt < 4; ++nt)
#pragma unroll
      for (int j = 0; j < 4; ++j) {
        int row = m0 + wm + mt*16 + quad*4 + j;
        int col = n0 + wn + nt*16 + l16;
        st(Cb + (long)row*HW + col, acc[mt][nt][j]);
      }
}

// ---------------------------------------------------------------------------
// Depthwise 3x3 SAME, IN-PLACE, one block per (channel, batch).
// SINGLE-PHASE: 512 threads stage the whole 128x128 plane (+zero halos) into
// LDS (130 rows x 140 shorts = 36.4 KB -> 4 blocks/CU, 32 waves = 100% occ),
// one __syncthreads, then branch-free conv from LDS with direct register
// stores (no LDS output round-trip). Row stride 140 shorts = 6-bank step
// (distinct banks across the 16 rows a wave reads -> only 2-way conflicts).
// LDS row layout: [0..3]=left zero pad (image col -4..-1), [4..131]=cols
// 0..127, [132..139]=right zero pad. LDS row 0 = image row -1 (zeros),
// rows 1..128 = image rows 0..127, row 129 = image row 128 (zeros).
__global__ __launch_bounds__(512, 8) void dwconv_inplace(
    bf16* __restrict__ qb, bf16* __restrict__ kvb,
    const float* __restrict__ Wdw, float* __restrict__ ssq)
{
  const int ch = blockIdx.x;   // 0..1151 (q:0..383, k:384..767, v:768..1151)
  const int b  = blockIdx.y;
  bf16* plane = (ch < DIM) ? qb + ((long)b*DIM + ch)*HW
                           : kvb + ((long)b*2*DIM + (ch - DIM))*HW;
  float w9[9];
#pragma unroll
  for (int i = 0; i < 9; ++i) w9[i] = Wdw[ch*9 + i];

  __shared__ short t_[130*140];   // 36400 B
  __shared__ float wsum[8];
  const int t = threadIdx.x;

  // stage full plane into registers (8 uint2 in flight per thread)
  uint2 v[8];
#pragma unroll
  for (int i = 0; i < 8; ++i) {
    int chunk = i*512 + t;               // 0..4095
    int r = chunk >> 5, c8 = chunk & 31;
    v[i] = *(const uint2*)(plane + r*128 + c8*4);
  }

  // zero halos (disjoint from data region):
  if (t < 74) {            // rows 0 and 129 full (37 uint2 each)
    int row = (t < 37) ? 0 : 129;
    int c4 = (t < 37) ? t : (t - 37);
    *(uint2*)&t_[row*140 + c4*4] = make_uint2(0u, 0u);
  }
  if (t < 128)             // left pads rows 1..128 (shorts 0..3)
    *(uint2*)&t_[(t+1)*140] = make_uint2(0u, 0u);
  {                        // right pads rows 1..128 (shorts 132..139): 256 uint2
    if (t < 256) {
      int row = (t >> 1) + 1, half = t & 1;
      *(uint2*)&t_[row*140 + 132 + half*4] = make_uint2(0u, 0u);
    }
  }

  // LDS staging writes
#pragma unroll
  for (int i = 0; i < 8; ++i) {
    int chunk = i*512 + t;
    int r = chunk >> 5, c8 = chunk & 31;
    *(uint2*)&t_[(r+1)*140 + 4 + c8*4] = v[i];
  }
  __syncthreads();

  // compute: thread -> output row r = t>>2 (0..127), column quarter q = t&3
  const int r = t >> 2, q = t & 3;
  const int c0 = q * 32;
  const short* rT = t_ + (r    )*140 + 4 + c0;   // image row r-1
  const short* rM = t_ + (r + 1)*140 + 4 + c0;   // image row r
  const short* rB = t_ + (r + 2)*140 + 4 + c0;   // image row r+1

  float at[4], am[4], ab[4];
  cvt4(rT, at); cvt4(rM, am); cvt4(rB, ab);
  float lt = s2f(rT[-1]), lm = s2f(rM[-1]), lb = s2f(rB[-1]);

  float ss = 0.f;
  unsigned p0 = 0, p1 = 0;
#pragma unroll
  for (int jb = 0; jb < 32; jb += 4) {
    float bt[4], bm[4], bb[4];
    cvt4(rT + jb + 4, bt);
    cvt4(rM + jb + 4, bm);
    cvt4(rB + jb + 4, bb);
    float o0 = w9[0]*lt    + w9[1]*at[0] + w9[2]*at[1]
             + w9[3]*lm    + w9[4]*am[0] + w9[5]*am[1]
             + w9[6]*lb    + w9[7]*ab[0] + w9[8]*ab[1];
    float o1 = w9[0]*at[0] + w9[1]*at[1] + w9[2]*at[2]
             + w9[3]*am[0] + w9[4]*am[1] + w9[5]*am[2]
             + w9[6]*ab[0] + w9[7]*ab[1] + w9[8]*ab[2];
    float o2 = w9[0]*at[1] + w9[1]*at[2] + w9[2]*at[3]
             + w9[3]*am[1] + w9[4]*am[2] + w9[5]*am[3]
             + w9[6]*ab[1] + w9[7]*ab[2] + w9[8]*ab[3];
    float o3 = w9[0]*at[2] + w9[1]*at[3] + w9[2]*bt[0]
             + w9[3]*am[2] + w9[4]*am[3] + w9[5]*bm[0]
             + w9[6]*ab[2] + w9[7]*ab[3] + w9[8]*bb[0];
    ss += o0*o0 + o1*o1 + o2*o2 + o3*o3;
    unsigned u0 = (unsigned)bfbits(o0) | ((unsigned)bfbits(o1) << 16);
    unsigned u1 = (unsigned)bfbits(o2) | ((unsigned)bfbits(o3) << 16);
    if ((jb & 4) == 0) { p0 = u0; p1 = u1; }
    else *(uint4*)(plane + r*128 + c0 + (jb - 4)) = make_uint4(p0, p1, u0, u1);
    lt = at[3]; lm = am[3]; lb = ab[3];
#pragma unroll
    for (int u2 = 0; u2 < 4; ++u2) { at[u2]=bt[u2]; am[u2]=bm[u2]; ab[u2]=bb[u2]; }
  }

  // ssq reduction (q/k channels only)
  if (ch < 2*DIM) {
#pragma unroll
    for (int off = 32; off; off >>= 1) ss += __shfl_down(ss, off);
    if ((t & 63) == 0) wsum[t >> 6] = ss;
    __syncthreads();
    if (t == 0) {
      float s = 0.f;
#pragma unroll
      for (int i = 0; i < 8; ++i) s += wsum[i];
      ssq[b*2*DIM + ch] = s;
    }
  }
}

// ---------------------------------------------------------------------------
// S slabs: Sp[split][b][h][48][48] = sum over this split's n-range of q.k^T
// 512 threads = 8 waves; slice = split*8 + wave; 256 n per slice (8 ksteps).
__global__ __launch_bounds__(512) void s_mfma(
    const bf16* __restrict__ qd, const bf16* __restrict__ kd,
    float* __restrict__ Sp)
{
  const int split = blockIdx.x;  // 0..7
  const int h = blockIdx.y, b = blockIdx.z;
  const int t = threadIdx.x, w = t >> 6, lane = t & 63;
  const int quad = lane >> 4, l16 = lane & 15;
  const bf16* qp = qd + ((long)b*DIM + h*CP)*HW;
  const bf16* kp = kd + ((long)b*DIM + h*CP)*HW;
  const int nbase = (split*8 + w) * 256;

  f32x4 acc[3][3] = {};
  for (int ks = 0; ks < 8; ++ks) {
    const int n = nbase + ks*32 + quad*8;
    bf16x8 aq[3], bk[3];
#pragma unroll
    for (int i = 0; i < 3; ++i) {
      aq[i] = *(const bf16x8*)(qp + (long)(i*16 + l16)*HW + n);
      bk[i] = *(const bf16x8*)(kp + (long)(i*16 + l16)*HW + n);
    }
#pragma unroll
    for (int i = 0; i < 3; ++i)
#pragma unroll
      for (int j = 0; j < 3; ++j)
        acc[i][j] = __builtin_amdgcn_mfma_f32_16x16x32_bf16(aq[i], bk[j], acc[i][j], 0, 0, 0);
  }

  __shared__ float Sred[8][CP*CP];
#pragma unroll
  for (int i = 0; i < 3; ++i)
#pragma unroll
    for (int j = 0; j < 3; ++j)
#pragma unroll
      for (int rr = 0; rr < 4; ++rr)
        Sred[w][(i*16 + quad*4 + rr)*CP + j*16 + l16] = acc[i][j][rr];
  __syncthreads();

  float* out = Sp + (long)split*(NB*HEADS*CP*CP) + ((long)(b*HEADS + h))*CP*CP;
  for (int g = t; g < CP*CP; g += 512) {
    float s = 0.f;
#pragma unroll
    for (int ww = 0; ww < 8; ++ww) s += Sred[ww][g];
    out[g] = s;
  }
}

// ---------------------------------------------------------------------------
// logit = (sum slabs) * rsqrt(ssq_q[c]) * rsqrt(ssq_k[d]) * temp[h]; softmax
// over d; writes into slab 0 (attn).
__global__ __launch_bounds__(64) void softmax_attn(
    float* __restrict__ Sp, const float* __restrict__ ssq,
    const float* __restrict__ temp)
{
  const int bhc = blockIdx.x;
  const int c = bhc % CP;
  const int h = (bhc / CP) % HEADS;
  const int b = bhc / (CP * HEADS);
  const int lane = threadIdx.x;
  const long rowoff = ((long)(b*HEADS + h))*CP*CP + c*CP;
  const float rq = rsqrtf(ssq[b*2*DIM + h*CP + c]);
  const float tmp = temp[h];
  float logit = -1e30f;
  if (lane < CP) {
    float s = 0.f;
#pragma unroll
    for (int sl = 0; sl < 8; ++sl) s += Sp[(long)sl*(NB*HEADS*CP*CP) + rowoff + lane];
    float rk = rsqrtf(ssq[b*2*DIM + DIM + h*CP + lane]);
    logit = s * rq * rk * tmp;
  }
  float m = logit;
#pragma unroll
  for (int off = 32; off; off >>= 1) m = fmaxf(m, __shfl_down(m, off));
  m = __shfl(m, 0);
  float e = (lane < CP) ? __expf(logit - m) : 0.f;
  float s = e;
#pragma unroll
  for (int off = 32; off; off >>= 1) s += __shfl_down(s, off);
  s = __shfl(s, 0);
  if (lane < CP) Sp[rowoff + lane] = e / s;
}

// ---------------------------------------------------------------------------
// W2[b, o, h*48+d] = sum_c Wproj[o, h*48+c] * attn[b,h,c,d]   (bf16 out)
__global__ __launch_bounds__(256) void w2fold(
    const float* __restrict__ attn, const float* __restrict__ Wproj,
    bf16* __restrict__ W2)
{
  const int ot = blockIdx.x;  // o-tile of 128 (3 tiles)
  const int h  = blockIdx.y;
  const int b  = blockIdx.z;
  __shared__ float at[CP][CP];
  __shared__ float wp[128][CP];
  const int t = threadIdx.x;
  const float* Ap = attn + ((long)(b*HEADS + h))*CP*CP;
#pragma unroll
  for (int i = 0; i < 9; ++i) {
    int idx = t + 256*i;
    at[idx / CP][idx % CP] = Ap[idx];
  }
#pragma unroll
  for (int i = 0; i < 24; ++i) {
    int idx = t + 256*i;
    int o = idx / CP, c = idx % CP;
    wp[o][c] = Wproj[(long)(ot*128 + o)*DIM + h*CP + c];
  }
  __syncthreads();
#pragma unroll
  for (int i = 0; i < 24; ++i) {
    int idx = t + 256*i;
    int o = idx / CP, d = idx % CP;
    float a = 0.f;
#pragma unroll
    for (int c = 0; c < CP; ++c) a += wp[o][c] * at[c][d];
    W2[((long)b*DIM + ot*128 + o)*DIM + h*CP + d] = f2bf(a);
  }
}

// ---------------------------------------------------------------------------
extern "C" void kernel_launch(void* const* d_in, const int* in_sizes, int n_in,
                              void* d_out, int out_size, void* d_ws, size_t ws_size,
                              hipStream_t stream) {
  const float* x     = (const float*)d_in[0];
  const float* y     = (const float*)d_in[1];
  const float* Wq    = (const float*)d_in[2];
  const float* Wkv   = (const float*)d_in[3];
  const float* Wdw   = (const float*)d_in[4];
  const float* Wproj = (const float*)d_in[5];
  const float* temp  = (const float*)d_in[6];
  float* out = (float*)d_out;

  char* ws = (char*)d_ws;
  const long SZ_T  = 50331648L;                 // one [HW][384] bf16 tensor per 4 batches
  bf16* xT    = (bf16*)(ws + 0L);               // later: vdT
  bf16* yT    = (bf16*)(ws + SZ_T);
  bf16* q_bf  = (bf16*)(ws + 2*SZ_T);           // dwconv in-place -> qd
  bf16* kv_bf = (bf16*)(ws + 3*SZ_T);           // 100663296; in-place -> kd, vd
  char* tail  = ws + 5*SZ_T;                    // 251658240
  bf16* Wq_bf  = (bf16*)(tail);                 // 294912   (dead before Sp)
  bf16* Wkv_bf = (bf16*)(tail + 294912L);       // 589824   (dead before Sp)
  float* Sp    = (float*)(tail);                // 8 slabs x 294912 = 2359296; slab0 -> attn
  bf16* W2_bf  = (bf16*)(tail + 294912L);       // 1179648  (over dead slabs 1-4)
  float* ssq   = (float*)(tail + 2359296L);     // 12288
  bf16* vdT    = xT;
  bf16* vd     = kv_bf + (long)DIM*HW;          // v slice base (batch stride 2*DIM*HW)

  // 1. weights -> bf16
  convert_w<<<864, 256, 0, stream>>>(Wq, Wkv, Wq_bf, Wkv_bf);
  // 2. x,y -> [hw][c] bf16
  transpose_cast<float><<<dim3(HW/64, DIM/64, 8), 256, 0, stream>>>(
      x, y, xT, yT, (long)DIM*HW, (long)HW*DIM);
  // 3. q = Wq @ x
  gemm_mfma<bf16><<<dim3(HW/128, DIM/128, NB), 256, 0, stream>>>(
      Wq_bf, 0, xT, q_bf, DIM, DIM);
  // 4. kv = Wkv @ y
  gemm_mfma<bf16><<<dim3(HW/128, 2*DIM/128, NB), 256, 0, stream>>>(
      Wkv_bf, 0, yT, kv_bf, 2*DIM, DIM);
  // 5. depthwise 3x3 in-place + ssq (single-phase, 512 thr, 36.4 KB LDS)
  dwconv_inplace<<<dim3(3*DIM, NB), 512, 0, stream>>>(q_bf, kv_bf, Wdw, ssq);
  // 6. vd -> [hw][c]
  transpose_cast<bf16><<<dim3(HW/64, DIM/64, NB), 256, 0, stream>>>(
      vd, nullptr, vdT, nullptr, (long)2*DIM*HW, (long)HW*DIM);
  // 7. raw scores (8 slabs)
  s_mfma<<<dim3(8, HEADS, NB), 512, 0, stream>>>(q_bf, kv_bf, Sp);
  // 8. softmax with folded l2norm + temperature (into slab 0)
  softmax_attn<<<dim3(NB*HEADS*CP), 64, 0, stream>>>(Sp, ssq, temp);
  // 9. fold Wproj through attn -> bf16
  w2fold<<<dim3(3, HEADS, NB), 256, 0, stream>>>(Sp, Wproj, W2_bf);
  // 10. out = W2 @ vd
  gemm_mfma<float><<<dim3(HW/128, DIM/128, NB), 256, 0, stream>>>(
      W2_bf, (long)DIM*DIM, vdT, out, DIM, DIM);
}